// Round 3
// baseline (223.104 us; speedup 1.0000x reference)
//
#include <hip/hip_runtime.h>
#include <hip/hip_bf16.h>
#include <math.h>

#define LENGTH 4096
#define BATCH  4096
#define CHUNK  8       // timesteps per thread
#define NTHR   512     // threads per block; NTHR*CHUNK == LENGTH (one block per row)
#define NWAVE  (NTHR / 64)

typedef float vf4 __attribute__((ext_vector_type(4)));

// max-plus 2x2 compose: D = A (x) B, D[k][l] = max_m A[k][m] + B[m][l]
__device__ __forceinline__ void mp_compose(
    float a00, float a01, float a10, float a11,
    float b00, float b01, float b10, float b11,
    float& d00, float& d01, float& d10, float& d11) {
  d00 = fmaxf(a00 + b00, a01 + b10);
  d01 = fmaxf(a00 + b01, a01 + b11);
  d10 = fmaxf(a10 + b00, a11 + b10);
  d11 = fmaxf(a10 + b01, a11 + b11);
}

// F <- (S (x) D_u) (x) F     (one timestep applied on the left)
__device__ __forceinline__ void mp_step(
    float& f00, float& f01, float& f10, float& f11, float ui, float q) {
  float a0l0 = f00 - ui, a1l0 = f10 + ui;  // a_m[l] = phi_m + F[m][l]
  float a0l1 = f01 - ui, a1l1 = f11 + ui;
  float n00 = fmaxf(a0l0 + q, a1l0 - q);
  float n10 = fmaxf(a0l0 - q, a1l0 + q);
  float n01 = fmaxf(a0l1 + q, a1l1 - q);
  float n11 = fmaxf(a0l1 - q, a1l1 + q);
  f00 = n00; f01 = n01; f10 = n10; f11 = n11;
}

__global__ __launch_bounds__(NTHR, 6) void chain_bp_kernel(
    const float* __restrict__ jp, const float* __restrict__ bp,
    const int* __restrict__ obs, float* __restrict__ out) {
  const int row  = blockIdx.x;
  const int tid  = threadIdx.x;
  const int lane = tid & 63;
  const int wv   = tid >> 6;

  const float j  = jp[0];
  const float q  = 0.25f * j;              // log psi diag; off-diag = -q
  const float u0 = 0.5f * bp[0];           // log phi[o=0][s=1] ; s=0 is -u
  const float u1 = 0.5f * bp[1];
  const float wb = -fabsf(q);              // w_base: 0vec == S (x) (wb,wb)

  // ---- load this thread's 8 observations (two int4) -> u[i] ----
  const int t0 = tid * CHUNK;
  const int4* op = reinterpret_cast<const int4*>(obs + (size_t)row * LENGTH + t0);
  float u[CHUNK];
#pragma unroll
  for (int v = 0; v < CHUNK / 4; ++v) {
    int4 o = op[v];
    u[4 * v + 0] = o.x ? u1 : u0;
    u[4 * v + 1] = o.y ? u1 : u0;
    u[4 * v + 2] = o.z ? u1 : u0;
    u[4 * v + 3] = o.w ? u1 : u0;
  }

  // ---- build chunk forward matrix F = M_{t0+7} (x) ... (x) M_{t0} ----
  // Two independent 4-step halves (2x ILP), composed once.
  float l00 = -u[0] + q, l01 = u[0] - q, l10 = -u[0] - q, l11 = u[0] + q;
  float h00 = -u[4] + q, h01 = u[4] - q, h10 = -u[4] - q, h11 = u[4] + q;
#pragma unroll
  for (int i = 1; i < 4; ++i) {
    mp_step(l00, l01, l10, l11, u[i], q);
    mp_step(h00, h01, h10, h11, u[4 + i], q);
  }
  float f00, f01, f10, f11;
  mp_compose(h00, h01, h10, h11, l00, l01, l10, l11, f00, f01, f10, f11);

  // ---- wave-level inclusive PREFIX scan X (decreasing order: current on LEFT) ----
  float x00 = f00, x01 = f01, x10 = f10, x11 = f11;
#pragma unroll
  for (int d = 1; d < 64; d <<= 1) {
    float p00 = __shfl_up(x00, d), p01 = __shfl_up(x01, d);
    float p10 = __shfl_up(x10, d), p11 = __shfl_up(x11, d);
    if (lane >= d) {
      float n00, n01, n10, n11;
      mp_compose(x00, x01, x10, x11, p00, p01, p10, p11, n00, n01, n10, n11);
      x00 = n00; x01 = n01; x10 = n10; x11 = n11;
    }
  }
  // ---- wave-level inclusive SUFFIX scan Y over Q = F^T (increasing order) ----
  float y00 = f00, y01 = f10, y10 = f01, y11 = f11;  // transpose
#pragma unroll
  for (int d = 1; d < 64; d <<= 1) {
    float p00 = __shfl_down(y00, d), p01 = __shfl_down(y01, d);
    float p10 = __shfl_down(y10, d), p11 = __shfl_down(y11, d);
    if (lane + d < 64) {
      float n00, n01, n10, n11;
      mp_compose(y00, y01, y10, y11, p00, p01, p10, p11, n00, n01, n10, n11);
      y00 = n00; y01 = n01; y10 = n10; y11 = n11;
    }
  }

  // ---- cross-wave stitch via tiny LDS ----
  __shared__ float smp[NWAVE][4];  // per-wave full prefix matrix (lane 63 of X)
  __shared__ float sms[NWAVE][4];  // per-wave full suffix matrix (lane 0 of Y)
  if (lane == 63) { smp[wv][0] = x00; smp[wv][1] = x01; smp[wv][2] = x10; smp[wv][3] = x11; }
  if (lane == 0)  { sms[wv][0] = y00; sms[wv][1] = y01; sms[wv][2] = y10; sms[wv][3] = y11; }
  __syncthreads();

  // fhead = W_{wv-1} (x) ... (x) W_0 (x) 0vec
  float fh0 = 0.f, fh1 = 0.f;
  for (int k = 0; k < wv; ++k) {
    float m00 = smp[k][0], m01 = smp[k][1], m10 = smp[k][2], m11 = smp[k][3];
    float n0 = fmaxf(m00 + fh0, m01 + fh1);
    float n1 = fmaxf(m10 + fh0, m11 + fh1);
    fh0 = n0; fh1 = n1;
  }
  // wtail = V_{wv+1} (x) ... (x) V_{NWAVE-1} (x) w_base
  float wt0 = wb, wt1 = wb;
  for (int k = NWAVE - 1; k > wv; --k) {
    float m00 = sms[k][0], m01 = sms[k][1], m10 = sms[k][2], m11 = sms[k][3];
    float n0 = fmaxf(m00 + wt0, m01 + wt1);
    float n1 = fmaxf(m10 + wt0, m11 + wt1);
    wt0 = n0; wt1 = n1;
  }

  // z_c = X_c (x) fhead = global fwd at start of NEXT chunk; f_in = z_{c-1}
  float z0 = fmaxf(x00 + fh0, x01 + fh1);
  float z1 = fmaxf(x10 + fh0, x11 + fh1);
  float zp0 = __shfl_up(z0, 1), zp1 = __shfl_up(z1, 1);
  float fi0 = (lane == 0) ? fh0 : zp0;
  float fi1 = (lane == 0) ? fh1 : zp1;

  // y_c = Y_c (x) wtail = w_{c-1}; w_c = y_{c+1} (lane 63 -> wtail)
  float yv0 = fmaxf(y00 + wt0, y01 + wt1);
  float yv1 = fmaxf(y10 + wt0, y11 + wt1);
  float yn0 = __shfl_down(yv0, 1), yn1 = __shfl_down(yv1, 1);
  float wc0 = (lane == 63) ? wt0 : yn0;
  float wc1 = (lane == 63) ? wt1 : yn1;
  // g_c = bwd at last t of this chunk = S (x) w_c
  float g0 = fmaxf(q + wc0, -q + wc1);
  float g1 = fmaxf(-q + wc0, q + wc1);

  // ---- in-chunk backward sweep (registers): b[i] = bwd[t0+i] ----
  float b0[CHUNK], b1[CHUNK];
  b0[CHUNK - 1] = g0; b1[CHUNK - 1] = g1;
#pragma unroll
  for (int i = CHUNK - 1; i > 0; --i) {
    // bwd[t-1] = M_t (x) bwd[t]
    float ui = u[i];
    float a0 = b0[i] - ui;
    float a1 = b1[i] + ui;
    b0[i - 1] = fmaxf(a0 + q, a1 - q);
    b1[i - 1] = fmaxf(a0 - q, a1 + q);
  }

  // ---- in-chunk forward sweep + belief + store (nontemporal float4) ----
  float* outp = out + (size_t)row * (2 * LENGTH) + t0;
  float fw0 = fi0, fw1 = fi1;
  vf4 acc0, acc1;
#pragma unroll
  for (int i = 0; i < CHUNK; ++i) {
    float ui = u[i];
    float e0 = __expf(-ui + fw0 + b0[i]);
    float e1 = __expf( ui + fw1 + b1[i]);
    acc0[i & 3] = e0;   // i is compile-time after unroll
    acc1[i & 3] = e1;
    if ((i & 3) == 3) {
      __builtin_nontemporal_store(acc0, reinterpret_cast<vf4*>(outp + (i - 3)));
      __builtin_nontemporal_store(acc1, reinterpret_cast<vf4*>(outp + LENGTH + (i - 3)));
    }
    // fwd[t+1] = M_t (x) fwd[t]
    float a0 = fw0 - ui, a1 = fw1 + ui;
    float n0 = fmaxf(a0 + q, a1 - q);
    float n1 = fmaxf(a0 - q, a1 + q);
    fw0 = n0; fw1 = n1;
  }
}

extern "C" void kernel_launch(void* const* d_in, const int* in_sizes, int n_in,
                              void* d_out, int out_size, void* d_ws, size_t ws_size,
                              hipStream_t stream) {
  const float* jp  = (const float*)d_in[0];   // scalar j
  const float* bp  = (const float*)d_in[1];   // b[2]
  const int*   obs = (const int*)d_in[2];     // [BATCH, LENGTH] int32
  float* out = (float*)d_out;                 // [BATCH, 2, LENGTH] fp32

  chain_bp_kernel<<<BATCH, NTHR, 0, stream>>>(jp, bp, obs, out);
}

// Round 4
// 190.438 us; speedup vs baseline: 1.1715x; 1.1715x over previous
//
#include <hip/hip_runtime.h>
#include <hip/hip_bf16.h>
#include <math.h>

#define LENGTH 4096
#define BATCH  4096
#define CHUNK  8       // timesteps per thread
#define NTHR   512     // threads per block; NTHR*CHUNK == LENGTH (one block per row)
#define NWAVE  (NTHR / 64)

typedef float vf4 __attribute__((ext_vector_type(4)));

// max-plus 2x2 compose: D = A (x) B, D[k][l] = max_m A[k][m] + B[m][l]
__device__ __forceinline__ void mp_compose(
    float a00, float a01, float a10, float a11,
    float b00, float b01, float b10, float b11,
    float& d00, float& d01, float& d10, float& d11) {
  d00 = fmaxf(a00 + b00, a01 + b10);
  d01 = fmaxf(a00 + b01, a01 + b11);
  d10 = fmaxf(a10 + b00, a11 + b10);
  d11 = fmaxf(a10 + b01, a11 + b11);
}

// F <- (S (x) D_u) (x) F     (one timestep applied on the left)
__device__ __forceinline__ void mp_step(
    float& f00, float& f01, float& f10, float& f11, float ui, float q) {
  float a0l0 = f00 - ui, a1l0 = f10 + ui;  // a_m[l] = phi_m + F[m][l]
  float a0l1 = f01 - ui, a1l1 = f11 + ui;
  float n00 = fmaxf(a0l0 + q, a1l0 - q);
  float n10 = fmaxf(a0l0 - q, a1l0 + q);
  float n01 = fmaxf(a0l1 + q, a1l1 - q);
  float n11 = fmaxf(a0l1 - q, a1l1 + q);
  f00 = n00; f01 = n01; f10 = n10; f11 = n11;
}

__global__ __launch_bounds__(NTHR, 8) void chain_bp_kernel(
    const float* __restrict__ jp, const float* __restrict__ bp,
    const int* __restrict__ obs, float* __restrict__ out) {
  const int row  = blockIdx.x;
  const int tid  = threadIdx.x;
  const int lane = tid & 63;
  const int wv   = tid >> 6;

  const float j  = jp[0];
  const float q  = 0.25f * j;              // log psi diag; off-diag = -q
  const float u0 = 0.5f * bp[0];           // log phi[o=0][s=1] ; s=0 is -u
  const float u1 = 0.5f * bp[1];
  const float wb = -fabsf(q);              // w_base: 0vec == S (x) (wb,wb)

  // ---- load this thread's 8 observations (two int4) -> u[i] ----
  const int t0 = tid * CHUNK;
  const int4* op = reinterpret_cast<const int4*>(obs + (size_t)row * LENGTH + t0);
  float u[CHUNK];
#pragma unroll
  for (int v = 0; v < CHUNK / 4; ++v) {
    int4 o = op[v];
    u[4 * v + 0] = o.x ? u1 : u0;
    u[4 * v + 1] = o.y ? u1 : u0;
    u[4 * v + 2] = o.z ? u1 : u0;
    u[4 * v + 3] = o.w ? u1 : u0;
  }

  // ---- build chunk forward matrix F = M_{t0+7} (x) ... (x) M_{t0} ----
  // Two independent 4-step halves (2x ILP), composed once.
  float l00 = -u[0] + q, l01 = u[0] - q, l10 = -u[0] - q, l11 = u[0] + q;
  float h00 = -u[4] + q, h01 = u[4] - q, h10 = -u[4] - q, h11 = u[4] + q;
#pragma unroll
  for (int i = 1; i < 4; ++i) {
    mp_step(l00, l01, l10, l11, u[i], q);
    mp_step(h00, h01, h10, h11, u[4 + i], q);
  }
  float f00, f01, f10, f11;
  mp_compose(h00, h01, h10, h11, l00, l01, l10, l11, f00, f01, f10, f11);

  // ---- wave-level inclusive PREFIX scan X (decreasing order: current on LEFT) ----
  float x00 = f00, x01 = f01, x10 = f10, x11 = f11;
#pragma unroll
  for (int d = 1; d < 64; d <<= 1) {
    float p00 = __shfl_up(x00, d), p01 = __shfl_up(x01, d);
    float p10 = __shfl_up(x10, d), p11 = __shfl_up(x11, d);
    if (lane >= d) {
      float n00, n01, n10, n11;
      mp_compose(x00, x01, x10, x11, p00, p01, p10, p11, n00, n01, n10, n11);
      x00 = n00; x01 = n01; x10 = n10; x11 = n11;
    }
  }
  // ---- wave-level inclusive SUFFIX scan Y over Q = F^T (increasing order) ----
  float y00 = f00, y01 = f10, y10 = f01, y11 = f11;  // transpose
#pragma unroll
  for (int d = 1; d < 64; d <<= 1) {
    float p00 = __shfl_down(y00, d), p01 = __shfl_down(y01, d);
    float p10 = __shfl_down(y10, d), p11 = __shfl_down(y11, d);
    if (lane + d < 64) {
      float n00, n01, n10, n11;
      mp_compose(y00, y01, y10, y11, p00, p01, p10, p11, n00, n01, n10, n11);
      y00 = n00; y01 = n01; y10 = n10; y11 = n11;
    }
  }

  // ---- cross-wave stitch via tiny LDS ----
  __shared__ float smp[NWAVE][4];  // per-wave full prefix matrix (lane 63 of X)
  __shared__ float sms[NWAVE][4];  // per-wave full suffix matrix (lane 0 of Y)
  if (lane == 63) { smp[wv][0] = x00; smp[wv][1] = x01; smp[wv][2] = x10; smp[wv][3] = x11; }
  if (lane == 0)  { sms[wv][0] = y00; sms[wv][1] = y01; sms[wv][2] = y10; sms[wv][3] = y11; }
  __syncthreads();

  // fhead = W_{wv-1} (x) ... (x) W_0 (x) 0vec
  float fh0 = 0.f, fh1 = 0.f;
  for (int k = 0; k < wv; ++k) {
    float m00 = smp[k][0], m01 = smp[k][1], m10 = smp[k][2], m11 = smp[k][3];
    float n0 = fmaxf(m00 + fh0, m01 + fh1);
    float n1 = fmaxf(m10 + fh0, m11 + fh1);
    fh0 = n0; fh1 = n1;
  }
  // wtail = V_{wv+1} (x) ... (x) V_{NWAVE-1} (x) w_base
  float wt0 = wb, wt1 = wb;
  for (int k = NWAVE - 1; k > wv; --k) {
    float m00 = sms[k][0], m01 = sms[k][1], m10 = sms[k][2], m11 = sms[k][3];
    float n0 = fmaxf(m00 + wt0, m01 + wt1);
    float n1 = fmaxf(m10 + wt0, m11 + wt1);
    wt0 = n0; wt1 = n1;
  }

  // z_c = X_c (x) fhead = global fwd at start of NEXT chunk; f_in = z_{c-1}
  float z0 = fmaxf(x00 + fh0, x01 + fh1);
  float z1 = fmaxf(x10 + fh0, x11 + fh1);
  float zp0 = __shfl_up(z0, 1), zp1 = __shfl_up(z1, 1);
  float fi0 = (lane == 0) ? fh0 : zp0;
  float fi1 = (lane == 0) ? fh1 : zp1;

  // y_c = Y_c (x) wtail = w_{c-1}; w_c = y_{c+1} (lane 63 -> wtail)
  float yv0 = fmaxf(y00 + wt0, y01 + wt1);
  float yv1 = fmaxf(y10 + wt0, y11 + wt1);
  float yn0 = __shfl_down(yv0, 1), yn1 = __shfl_down(yv1, 1);
  float wc0 = (lane == 63) ? wt0 : yn0;
  float wc1 = (lane == 63) ? wt1 : yn1;
  // g_c = bwd at last t of this chunk = S (x) w_c
  float g0 = fmaxf(q + wc0, -q + wc1);
  float g1 = fmaxf(-q + wc0, q + wc1);

  // ---- in-chunk backward sweep (registers): b[i] = bwd[t0+i] ----
  float b0[CHUNK], b1[CHUNK];
  b0[CHUNK - 1] = g0; b1[CHUNK - 1] = g1;
#pragma unroll
  for (int i = CHUNK - 1; i > 0; --i) {
    // bwd[t-1] = M_t (x) bwd[t]
    float ui = u[i];
    float a0 = b0[i] - ui;
    float a1 = b1[i] + ui;
    b0[i - 1] = fmaxf(a0 + q, a1 - q);
    b1[i - 1] = fmaxf(a0 - q, a1 + q);
  }

  // ---- in-chunk forward sweep + belief; buffer, then 4 adjacent stores ----
  float fw0 = fi0, fw1 = fi1;
  vf4 p0lo, p0hi, p1lo, p1hi;  // plane0/plane1, elements 0..3 / 4..7
#pragma unroll
  for (int i = 0; i < CHUNK; ++i) {
    float ui = u[i];
    float e0 = __expf(-ui + fw0 + b0[i]);
    float e1 = __expf( ui + fw1 + b1[i]);
    if (i < 4) { p0lo[i] = e0; p1lo[i] = e1; }
    else       { p0hi[i - 4] = e0; p1hi[i - 4] = e1; }
    // fwd[t+1] = M_t (x) fwd[t]
    float a0 = fw0 - ui, a1 = fw1 + ui;
    float n0 = fmaxf(a0 + q, a1 - q);
    float n1 = fmaxf(a0 - q, a1 + q);
    fw0 = n0; fw1 = n1;
  }
  float* outp = out + (size_t)row * (2 * LENGTH) + t0;
  *reinterpret_cast<vf4*>(outp)              = p0lo;
  *reinterpret_cast<vf4*>(outp + 4)          = p0hi;
  *reinterpret_cast<vf4*>(outp + LENGTH)     = p1lo;
  *reinterpret_cast<vf4*>(outp + LENGTH + 4) = p1hi;
}

extern "C" void kernel_launch(void* const* d_in, const int* in_sizes, int n_in,
                              void* d_out, int out_size, void* d_ws, size_t ws_size,
                              hipStream_t stream) {
  const float* jp  = (const float*)d_in[0];   // scalar j
  const float* bp  = (const float*)d_in[1];   // b[2]
  const int*   obs = (const int*)d_in[2];     // [BATCH, LENGTH] int32
  float* out = (float*)d_out;                 // [BATCH, 2, LENGTH] fp32

  chain_bp_kernel<<<BATCH, NTHR, 0, stream>>>(jp, bp, obs, out);
}